// Round 2
// baseline (250.225 us; speedup 1.0000x reference)
//
#include <hip/hip_runtime.h>

#define SEQ   2000
#define TAPS  7
#define CH    128
#define BATCH 32
#define C4    (CH / 4)   // 32 float4 per channel row

typedef float f4 __attribute__((ext_vector_type(4)));  // clang-native vec4

// Block = 256 threads = 8 seq-rows x 32 float4-lanes. Grid = (SEQ/8, BATCH).
// Each thread handles one (b, i, c4) and writes all 7 taps:
//   out[b, i, j, c] = x[b, i-6+j, c]  (0 if index < 0)
__global__ __launch_bounds__(256) void conv_window_kernel(
    const float* __restrict__ x, float* __restrict__ out) {
    const int r  = threadIdx.x >> 5;          // 0..7: seq row within block
    const int c4 = threadIdx.x & 31;          // 0..31: float4 index in channel dim
    const int i  = blockIdx.x * 8 + r;        // 0..1999
    const int b  = blockIdx.y;                // 0..31

    const f4* __restrict__ xb =
        reinterpret_cast<const f4*>(x) + (size_t)b * SEQ * C4 + c4;
    f4* __restrict__ orow =
        reinterpret_cast<f4*>(out) + ((size_t)b * SEQ + i) * TAPS * C4 + c4;

    const f4 zero = {0.f, 0.f, 0.f, 0.f};
#pragma unroll
    for (int j = 0; j < TAPS; ++j) {
        const int src = i - (TAPS - 1) + j;           // i-6 .. i
        const int srcc = src < 0 ? 0 : src;           // clamp address (always valid)
        f4 v = xb[(size_t)srcc * C4];                 // cached read (L2/L3-resident)
        if (src < 0) v = zero;                        // branchless select to zero
        __builtin_nontemporal_store(v, &orow[(size_t)j * C4]);  // streaming write
    }
}

extern "C" void kernel_launch(void* const* d_in, const int* in_sizes, int n_in,
                              void* d_out, int out_size, void* d_ws, size_t ws_size,
                              hipStream_t stream) {
    const float* x = (const float*)d_in[0];
    float* out = (float*)d_out;
    dim3 grid(SEQ / 8, BATCH);   // 250 x 32 = 8000 blocks
    conv_window_kernel<<<grid, 256, 0, stream>>>(x, out);
}